// Round 1
// baseline (2354.965 us; speedup 1.0000x reference)
//
#include <hip/hip_runtime.h>

#define NB 2048
#define NT 512
#define NF 64
#define NH 20
#define NG 80          // 4*H
#define TC 8           // timesteps per chunk
#define NCHUNK (NT/TC) // 64
#define BPB 3          // batch rows per block
#define NBLK ((NB + BPB - 1)/BPB)  // 683

__device__ __forceinline__ float sigm(float v)   { return 1.0f / (1.0f + __expf(-v)); }
__device__ __forceinline__ float tanh_f(float v) { return 1.0f - 2.0f / (1.0f + __expf(2.0f * v)); }

__global__ __launch_bounds__(256, 3) void mv_lstm_fused(
    const float* __restrict__ x, const float* __restrict__ W_ih,
    const float* __restrict__ W_hh, const float* __restrict__ b_ih,
    const float* __restrict__ b_hh, const float* __restrict__ W_lin,
    const float* __restrict__ b_lin, float* __restrict__ out)
{
    __shared__ float w_s[NG][68];          // W_ih, padded stride (bank-conflict-free b128 reads)
    __shared__ float x_s[2][BPB*TC][68];   // x chunk, double buffered
    __shared__ float p_s[2][BPB*TC][84];   // pre chunk, double buffered
    __shared__ float bias_s[NG];

    const int tid = threadIdx.x;
    const int b0  = blockIdx.x * BPB;
    const int wtid = tid - 64;             // GEMM-thread id for waves 1..3 (0..191)

    // ---------------- prologue staging ----------------
    for (int i = tid; i < NG * 16; i += 256) {
        int r = i >> 4, k4 = i & 15;
        *(float4*)&w_s[r][k4 * 4] = *(const float4*)(W_ih + r * NF + k4 * 4);
    }
    if (tid < NG) bias_s[tid] = b_ih[tid] + b_hh[tid];

    auto stage_x = [&](int cc, int xb) {   // waves 1..3 only: 24 rows x 16 float4
        #pragma unroll
        for (int p = 0; p < 2; ++p) {
            int id = wtid + p * 192;
            int r = id >> 4, k4 = id & 15;
            int bb = b0 + r / TC;
            int tt = cc * TC + (r % TC);
            float4 v = make_float4(0.f, 0.f, 0.f, 0.f);
            if (bb < NB) v = *(const float4*)(x + (bb * NT + tt) * NF + k4 * 4);
            *(float4*)&x_s[xb][r][k4 * 4] = v;
        }
    };

    auto do_gemm = [&](int buf) {          // waves 1..3: [24 x 64] @ [64 x 80] -> p_s[buf]
        int ty = wtid >> 4, tx = wtid & 15;   // ty 0..11 (2 rows each), tx 0..15 (5 cols each)
        float acc[2][5] = {{0,0,0,0,0},{0,0,0,0,0}};
        #pragma unroll
        for (int k4 = 0; k4 < 16; ++k4) {
            float4 xv[2], wv[5];
            #pragma unroll
            for (int i = 0; i < 2; ++i) xv[i] = *(const float4*)&x_s[buf][2*ty+i][k4*4];
            #pragma unroll
            for (int j5 = 0; j5 < 5; ++j5) wv[j5] = *(const float4*)&w_s[5*tx+j5][k4*4];
            #pragma unroll
            for (int i = 0; i < 2; ++i)
                #pragma unroll
                for (int j5 = 0; j5 < 5; ++j5)
                    acc[i][j5] += xv[i].x*wv[j5].x + xv[i].y*wv[j5].y
                                + xv[i].z*wv[j5].z + xv[i].w*wv[j5].w;
        }
        #pragma unroll
        for (int i = 0; i < 2; ++i)
            #pragma unroll
            for (int j5 = 0; j5 < 5; ++j5)
                p_s[buf][2*ty+i][5*tx+j5] = acc[i][j5] + bias_s[5*tx+j5];
    };

    // ------------- recurrence registers (wave 0) -------------
    int bL = tid / NH; if (bL > 2) bL = 2;     // lanes 60..63 clamp (results discarded)
    const int j = tid % NH;
    float wi[NH], wf[NH], wg[NH], wo[NH];
    float ht = 0.f, creg = 0.f, accum = 0.f;

    if (tid < 64) {
        // W_hh rows j, 20+j, 40+j, 60+j  (each 20 floats, 16B aligned)
        #pragma unroll
        for (int q = 0; q < 5; ++q) {
            float4 v0 = *(const float4*)(W_hh + (j)        * NH + q * 4);
            float4 v1 = *(const float4*)(W_hh + (NH   + j) * NH + q * 4);
            float4 v2 = *(const float4*)(W_hh + (2*NH + j) * NH + q * 4);
            float4 v3 = *(const float4*)(W_hh + (3*NH + j) * NH + q * 4);
            wi[q*4+0]=v0.x; wi[q*4+1]=v0.y; wi[q*4+2]=v0.z; wi[q*4+3]=v0.w;
            wf[q*4+0]=v1.x; wf[q*4+1]=v1.y; wf[q*4+2]=v1.z; wf[q*4+3]=v1.w;
            wg[q*4+0]=v2.x; wg[q*4+1]=v2.y; wg[q*4+2]=v2.z; wg[q*4+3]=v2.w;
            wo[q*4+0]=v3.x; wo[q*4+1]=v3.y; wo[q*4+2]=v3.z; wo[q*4+3]=v3.w;
        }
    } else {
        stage_x(0, 0);
    }
    __syncthreads();
    if (tid >= 64) {
        do_gemm(0);
        stage_x(1, 1);
    }
    __syncthreads();

    // ---------------- main pipeline ----------------
    for (int c = 0; c < NCHUNK; ++c) {
        if (tid < 64) {
            const int pb = c & 1;
            float wl[TC];
            #pragma unroll
            for (int tL = 0; tL < TC; ++tL) wl[tL] = W_lin[(c * TC + tL) * NH + j];
            #pragma unroll
            for (int tL = 0; tL < TC; ++tL) {
                const float* pr = &p_s[pb][bL * TC + tL][0];
                float s0 = pr[j];
                float s1 = pr[j + 20];
                float s2 = pr[j + 40];
                float s3 = pr[j + 60];
                #pragma unroll
                for (int k = 0; k < NH; ++k) {
                    float hk = __shfl(ht, bL * NH + k, 64);
                    s0 += wi[k] * hk;
                    s1 += wf[k] * hk;
                    s2 += wg[k] * hk;
                    s3 += wo[k] * hk;
                }
                float gi = sigm(s0);
                float gf = sigm(s1);
                float gg = tanh_f(s2);
                float go = sigm(s3);
                creg = gf * creg + gi * gg;
                ht   = go * tanh_f(creg);
                accum = fmaf(ht, wl[tL], accum);
            }
        } else {
            float4 xr0, xr1;
            const bool doStage = (c + 2 < NCHUNK);
            if (doStage) {  // issue global loads for chunk c+2 early
                #pragma unroll
                for (int p = 0; p < 2; ++p) {
                    int id = wtid + p * 192;
                    int r = id >> 4, k4 = id & 15;
                    int bb = b0 + r / TC;
                    int tt = (c + 2) * TC + (r % TC);
                    float4 v = make_float4(0.f, 0.f, 0.f, 0.f);
                    if (bb < NB) v = *(const float4*)(x + (bb * NT + tt) * NF + k4 * 4);
                    if (p == 0) xr0 = v; else xr1 = v;
                }
            }
            if (c + 1 < NCHUNK) do_gemm((c + 1) & 1);
            if (doStage) {
                #pragma unroll
                for (int p = 0; p < 2; ++p) {
                    int id = wtid + p * 192;
                    int r = id >> 4, k4 = id & 15;
                    *(float4*)&x_s[c & 1][r][k4 * 4] = (p == 0) ? xr0 : xr1;
                }
            }
        }
        __syncthreads();
    }

    // ---------------- epilogue: out[b] = sum_j accum + b_lin ----------------
    if (tid < 64) {
        float tot = 0.f;
        #pragma unroll
        for (int k = 0; k < NH; ++k) tot += __shfl(accum, bL * NH + k, 64);
        if (j == 0 && tid < 60 && (b0 + bL) < NB) out[b0 + bL] = tot + b_lin[0];
    }
}

extern "C" void kernel_launch(void* const* d_in, const int* in_sizes, int n_in,
                              void* d_out, int out_size, void* d_ws, size_t ws_size,
                              hipStream_t stream) {
    const float* x     = (const float*)d_in[0];
    const float* W_ih  = (const float*)d_in[1];
    const float* W_hh  = (const float*)d_in[2];
    const float* b_ih  = (const float*)d_in[3];
    const float* b_hh  = (const float*)d_in[4];
    const float* W_lin = (const float*)d_in[5];
    const float* b_lin = (const float*)d_in[6];
    float* outp = (float*)d_out;
    mv_lstm_fused<<<NBLK, 256, 0, stream>>>(x, W_ih, W_hh, b_ih, b_hh, W_lin, b_lin, outp);
}

// Round 2
// 2269.863 us; speedup vs baseline: 1.0375x; 1.0375x over previous
//
#include <hip/hip_runtime.h>

#define NB 2048
#define NT 512
#define NF 64
#define NH 20
#define NG 80          // 4*H
#define TC 8           // timesteps per chunk
#define NCHUNK (NT/TC) // 64
#define BPB 3          // batch rows per block
#define NBLK ((NB + BPB - 1)/BPB)  // 683
#define PSTR 85        // p_s row stride (pad: 8*85 % 32 != 0 -> slots on different banks)

__device__ __forceinline__ float sigm(float v)   { return 1.0f / (1.0f + __expf(-v)); }
__device__ __forceinline__ float tanh_f(float v) { return 1.0f - 2.0f / (1.0f + __expf(2.0f * v)); }

__global__ __launch_bounds__(256, 3) void mv_lstm_fused(
    const float* __restrict__ x, const float* __restrict__ W_ih,
    const float* __restrict__ W_hh, const float* __restrict__ b_ih,
    const float* __restrict__ b_hh, const float* __restrict__ W_lin,
    const float* __restrict__ b_lin, float* __restrict__ out)
{
    __shared__ float w_s[NG][68];            // W_ih, padded stride
    __shared__ float x_s[2][BPB*TC][68];     // x chunk, double buffered
    __shared__ float p_s[2][BPB*TC][PSTR];   // pre chunk, double buffered
    __shared__ float bias_s[NG];

    const int tid = threadIdx.x;
    const int b0  = blockIdx.x * BPB;
    const int wtid = tid - 64;               // GEMM-thread id for waves 1..3 (0..191)

    // ---------------- prologue staging ----------------
    for (int i = tid; i < NG * 16; i += 256) {
        int r = i >> 4, k4 = i & 15;
        *(float4*)&w_s[r][k4 * 4] = *(const float4*)(W_ih + r * NF + k4 * 4);
    }
    if (tid < NG) bias_s[tid] = b_ih[tid] + b_hh[tid];

    auto stage_x = [&](int cc, int xb) {     // waves 1..3 only: 24 rows x 16 float4
        #pragma unroll
        for (int p = 0; p < 2; ++p) {
            int id = wtid + p * 192;
            int r = id >> 4, k4 = id & 15;
            int bb = b0 + r / TC;
            int tt = cc * TC + (r % TC);
            float4 v = make_float4(0.f, 0.f, 0.f, 0.f);
            if (bb < NB) v = *(const float4*)(x + (bb * NT + tt) * NF + k4 * 4);
            *(float4*)&x_s[xb][r][k4 * 4] = v;
        }
    };

    auto do_gemm = [&](int buf) {            // waves 1..3: [24 x 64] @ [64 x 80] -> p_s[buf]
        int ty = wtid >> 4, tx = wtid & 15;  // ty 0..11 (2 rows each), tx 0..15 (5 cols each)
        float acc[2][5] = {{0,0,0,0,0},{0,0,0,0,0}};
        #pragma unroll
        for (int k4 = 0; k4 < 16; ++k4) {
            float4 xv[2], wv[5];
            #pragma unroll
            for (int i = 0; i < 2; ++i) xv[i] = *(const float4*)&x_s[buf][2*ty+i][k4*4];
            #pragma unroll
            for (int j5 = 0; j5 < 5; ++j5) wv[j5] = *(const float4*)&w_s[5*tx+j5][k4*4];
            #pragma unroll
            for (int i = 0; i < 2; ++i)
                #pragma unroll
                for (int j5 = 0; j5 < 5; ++j5)
                    acc[i][j5] += xv[i].x*wv[j5].x + xv[i].y*wv[j5].y
                                + xv[i].z*wv[j5].z + xv[i].w*wv[j5].w;
        }
        #pragma unroll
        for (int i = 0; i < 2; ++i)
            #pragma unroll
            for (int j5 = 0; j5 < 5; ++j5)
                p_s[buf][2*ty+i][5*tx+j5] = acc[i][j5] + bias_s[5*tx+j5];
    };

    // ------------- recurrence registers (wave 0) -------------
    // NO local arrays anywhere in this path: 20 explicit float4 weight regs.
    int bL = tid / NH; if (bL > 2) bL = 2;   // lanes 60..63 clamp (results discarded)
    const int j = tid % NH;
    const int base = bL * NH;
    float4 wi0, wi1, wi2, wi3, wi4;
    float4 wf0, wf1, wf2, wf3, wf4;
    float4 wg0, wg1, wg2, wg3, wg4;
    float4 wo0, wo1, wo2, wo3, wo4;
    float ht = 0.f, creg = 0.f, accum = 0.f;

    if (tid < 64) {
        const float* r0 = W_hh + (j)          * NH;
        const float* r1 = W_hh + (NH   + j)   * NH;
        const float* r2 = W_hh + (2*NH + j)   * NH;
        const float* r3 = W_hh + (3*NH + j)   * NH;
        wi0 = *(const float4*)(r0 + 0);  wi1 = *(const float4*)(r0 + 4);
        wi2 = *(const float4*)(r0 + 8);  wi3 = *(const float4*)(r0 + 12);
        wi4 = *(const float4*)(r0 + 16);
        wf0 = *(const float4*)(r1 + 0);  wf1 = *(const float4*)(r1 + 4);
        wf2 = *(const float4*)(r1 + 8);  wf3 = *(const float4*)(r1 + 12);
        wf4 = *(const float4*)(r1 + 16);
        wg0 = *(const float4*)(r2 + 0);  wg1 = *(const float4*)(r2 + 4);
        wg2 = *(const float4*)(r2 + 8);  wg3 = *(const float4*)(r2 + 12);
        wg4 = *(const float4*)(r2 + 16);
        wo0 = *(const float4*)(r3 + 0);  wo1 = *(const float4*)(r3 + 4);
        wo2 = *(const float4*)(r3 + 8);  wo3 = *(const float4*)(r3 + 12);
        wo4 = *(const float4*)(r3 + 16);
    } else {
        stage_x(0, 0);
    }
    __syncthreads();
    if (tid >= 64) {
        do_gemm(0);
        stage_x(1, 1);
    }
    __syncthreads();

    // 4 shuffles + 16 FMAs, split accumulators (a/b) to halve the dep chain
#define K4(VWI, VWF, VWG, VWO, KB)                                            \
    {                                                                         \
        float hk0 = __shfl(ht, base + (KB) + 0, 64);                          \
        float hk1 = __shfl(ht, base + (KB) + 1, 64);                          \
        float hk2 = __shfl(ht, base + (KB) + 2, 64);                          \
        float hk3 = __shfl(ht, base + (KB) + 3, 64);                          \
        s0a = fmaf(VWI.x, hk0, s0a); s0b = fmaf(VWI.y, hk1, s0b);             \
        s0a = fmaf(VWI.z, hk2, s0a); s0b = fmaf(VWI.w, hk3, s0b);             \
        s1a = fmaf(VWF.x, hk0, s1a); s1b = fmaf(VWF.y, hk1, s1b);             \
        s1a = fmaf(VWF.z, hk2, s1a); s1b = fmaf(VWF.w, hk3, s1b);             \
        s2a = fmaf(VWG.x, hk0, s2a); s2b = fmaf(VWG.y, hk1, s2b);             \
        s2a = fmaf(VWG.z, hk2, s2a); s2b = fmaf(VWG.w, hk3, s2b);             \
        s3a = fmaf(VWO.x, hk0, s3a); s3b = fmaf(VWO.y, hk1, s3b);             \
        s3a = fmaf(VWO.z, hk2, s3a); s3b = fmaf(VWO.w, hk3, s3b);             \
    }

#define TSTEP(TL, WL)                                                         \
    {                                                                         \
        const float* pr = pc + (TL) * PSTR;                                   \
        float s0a = pr[j],      s0b = 0.f;                                    \
        float s1a = pr[j + 20], s1b = 0.f;                                    \
        float s2a = pr[j + 40], s2b = 0.f;                                    \
        float s3a = pr[j + 60], s3b = 0.f;                                    \
        K4(wi0, wf0, wg0, wo0, 0)  K4(wi1, wf1, wg1, wo1, 4)                  \
        K4(wi2, wf2, wg2, wo2, 8)  K4(wi3, wf3, wg3, wo3, 12)                 \
        K4(wi4, wf4, wg4, wo4, 16)                                            \
        float gi = sigm(s0a + s0b);                                           \
        float gf = sigm(s1a + s1b);                                           \
        float gg = tanh_f(s2a + s2b);                                         \
        float go = sigm(s3a + s3b);                                           \
        creg = gf * creg + gi * gg;                                           \
        ht   = go * tanh_f(creg);                                             \
        accum = fmaf(ht, (WL), accum);                                        \
    }

    // ---------------- main pipeline ----------------
    for (int c = 0; c < NCHUNK; ++c) {
        if (tid < 64) {
            const int pb = c & 1;
            const float* wlp = W_lin + c * TC * NH + j;
            float wl0 = wlp[0 * NH], wl1 = wlp[1 * NH], wl2 = wlp[2 * NH], wl3 = wlp[3 * NH];
            float wl4 = wlp[4 * NH], wl5 = wlp[5 * NH], wl6 = wlp[6 * NH], wl7 = wlp[7 * NH];
            const float* pc = &p_s[pb][bL * TC][0];
            TSTEP(0, wl0) TSTEP(1, wl1) TSTEP(2, wl2) TSTEP(3, wl3)
            TSTEP(4, wl4) TSTEP(5, wl5) TSTEP(6, wl6) TSTEP(7, wl7)
        } else {
            float4 xr0, xr1;
            const bool doStage = (c + 2 < NCHUNK);
            if (doStage) {  // issue global loads for chunk c+2 early
                #pragma unroll
                for (int p = 0; p < 2; ++p) {
                    int id = wtid + p * 192;
                    int r = id >> 4, k4 = id & 15;
                    int bb = b0 + r / TC;
                    int tt = (c + 2) * TC + (r % TC);
                    float4 v = make_float4(0.f, 0.f, 0.f, 0.f);
                    if (bb < NB) v = *(const float4*)(x + (bb * NT + tt) * NF + k4 * 4);
                    if (p == 0) xr0 = v; else xr1 = v;
                }
            }
            if (c + 1 < NCHUNK) do_gemm((c + 1) & 1);
            if (doStage) {
                #pragma unroll
                for (int p = 0; p < 2; ++p) {
                    int id = wtid + p * 192;
                    int r = id >> 4, k4 = id & 15;
                    *(float4*)&x_s[c & 1][r][k4 * 4] = (p == 0) ? xr0 : xr1;
                }
            }
        }
        __syncthreads();
    }

    // ---------------- epilogue: out[b] = sum_j accum + b_lin ----------------
    if (tid < 64) {
        float tot = 0.f;
        #pragma unroll
        for (int k = 0; k < NH; ++k) tot += __shfl(accum, base + k, 64);
        if (j == 0 && tid < 60 && (b0 + bL) < NB) out[b0 + bL] = tot + b_lin[0];
    }
}

extern "C" void kernel_launch(void* const* d_in, const int* in_sizes, int n_in,
                              void* d_out, int out_size, void* d_ws, size_t ws_size,
                              hipStream_t stream) {
    const float* x     = (const float*)d_in[0];
    const float* W_ih  = (const float*)d_in[1];
    const float* W_hh  = (const float*)d_in[2];
    const float* b_ih  = (const float*)d_in[3];
    const float* b_hh  = (const float*)d_in[4];
    const float* W_lin = (const float*)d_in[5];
    const float* b_lin = (const float*)d_in[6];
    float* outp = (float*)d_out;
    mv_lstm_fused<<<NBLK, 256, 0, stream>>>(x, W_ih, W_hh, b_ih, b_hh, W_lin, b_lin, outp);
}

// Round 3
// 803.630 us; speedup vs baseline: 2.9304x; 2.8245x over previous
//
#include <hip/hip_runtime.h>

#define NB 2048
#define NT 512
#define NF 64
#define NH 20
#define NG 80          // 4*H
#define TC 8           // timesteps per chunk
#define NCHUNK (NT/TC) // 64
#define BPB 3          // batch rows per block
#define NBLK ((NB + BPB - 1)/BPB)  // 683
#define PSTR 85        // p_s row stride

__device__ __forceinline__ float sigm(float v)   { return 1.0f / (1.0f + __expf(-v)); }
__device__ __forceinline__ float tanh_f(float v) { return 1.0f - 2.0f / (1.0f + __expf(2.0f * v)); }

// Opaque register barrier: forces the value into VGPRs and prevents the
// allocator from rematerializing (re-loading) it instead of keeping it live.
#define OPAQ4(v) asm volatile("" : "+v"(v.x), "+v"(v.y), "+v"(v.z), "+v"(v.w))

__global__ __launch_bounds__(256, 3) void mv_lstm_fused(
    const float* __restrict__ x, const float* __restrict__ W_ih,
    const float* __restrict__ W_hh, const float* __restrict__ b_ih,
    const float* __restrict__ b_hh, const float* __restrict__ W_lin,
    const float* __restrict__ b_lin, float* __restrict__ out)
{
    __shared__ float w_s[NG][68];            // W_ih, padded stride
    __shared__ float x_s[2][BPB*TC][68];     // x chunk, double buffered
    __shared__ float p_s[2][BPB*TC][PSTR];   // pre chunk, double buffered
    __shared__ float bias_s[NG];

    const int tid = threadIdx.x;
    const int b0  = blockIdx.x * BPB;
    const int wtid = tid - 64;               // GEMM-thread id for waves 1..3 (0..191)

    // ---------------- prologue staging ----------------
    for (int i = tid; i < NG * 16; i += 256) {
        int r = i >> 4, k4 = i & 15;
        *(float4*)&w_s[r][k4 * 4] = *(const float4*)(W_ih + r * NF + k4 * 4);
    }
    if (tid < NG) bias_s[tid] = b_ih[tid] + b_hh[tid];

    auto stage_x = [&](int cc, int xb) {     // waves 1..3 only: 24 rows x 16 float4
        {
            int r = wtid >> 4, k4 = wtid & 15;
            int bb = b0 + (r >> 3);
            int tt = cc * TC + (r & 7);
            float4 v = make_float4(0.f, 0.f, 0.f, 0.f);
            if (bb < NB) v = *(const float4*)(x + ((size_t)bb * NT + tt) * NF + k4 * 4);
            *(float4*)&x_s[xb][r][k4 * 4] = v;
        }
        {
            int id = wtid + 192;
            int r = id >> 4, k4 = id & 15;
            int bb = b0 + (r >> 3);
            int tt = cc * TC + (r & 7);
            float4 v = make_float4(0.f, 0.f, 0.f, 0.f);
            if (bb < NB) v = *(const float4*)(x + ((size_t)bb * NT + tt) * NF + k4 * 4);
            *(float4*)&x_s[xb][r][k4 * 4] = v;
        }
    };

    // GEMM with NO local arrays: 10 explicit scalar accumulators.
    auto do_gemm = [&](int buf) {            // waves 1..3: [24 x 64] @ [64 x 80] -> p_s[buf]
        const int ty = wtid >> 4, tx = wtid & 15;  // ty 0..11 (2 rows), tx 0..15 (5 cols)
        float a00=0.f,a01=0.f,a02=0.f,a03=0.f,a04=0.f;
        float a10=0.f,a11=0.f,a12=0.f,a13=0.f,a14=0.f;
        const float* xr0p = &x_s[buf][2*ty+0][0];
        const float* xr1p = &x_s[buf][2*ty+1][0];
        const float* wp0 = &w_s[5*tx+0][0];
        const float* wp1 = &w_s[5*tx+1][0];
        const float* wp2 = &w_s[5*tx+2][0];
        const float* wp3 = &w_s[5*tx+3][0];
        const float* wp4 = &w_s[5*tx+4][0];
        #pragma unroll
        for (int k4 = 0; k4 < 16; ++k4) {
            float4 xv0 = *(const float4*)(xr0p + k4*4);
            float4 xv1 = *(const float4*)(xr1p + k4*4);
            float4 w0  = *(const float4*)(wp0  + k4*4);
            float4 w1  = *(const float4*)(wp1  + k4*4);
            float4 w2  = *(const float4*)(wp2  + k4*4);
            float4 w3  = *(const float4*)(wp3  + k4*4);
            float4 w4  = *(const float4*)(wp4  + k4*4);
            a00=fmaf(xv0.x,w0.x,a00); a00=fmaf(xv0.y,w0.y,a00); a00=fmaf(xv0.z,w0.z,a00); a00=fmaf(xv0.w,w0.w,a00);
            a01=fmaf(xv0.x,w1.x,a01); a01=fmaf(xv0.y,w1.y,a01); a01=fmaf(xv0.z,w1.z,a01); a01=fmaf(xv0.w,w1.w,a01);
            a02=fmaf(xv0.x,w2.x,a02); a02=fmaf(xv0.y,w2.y,a02); a02=fmaf(xv0.z,w2.z,a02); a02=fmaf(xv0.w,w2.w,a02);
            a03=fmaf(xv0.x,w3.x,a03); a03=fmaf(xv0.y,w3.y,a03); a03=fmaf(xv0.z,w3.z,a03); a03=fmaf(xv0.w,w3.w,a03);
            a04=fmaf(xv0.x,w4.x,a04); a04=fmaf(xv0.y,w4.y,a04); a04=fmaf(xv0.z,w4.z,a04); a04=fmaf(xv0.w,w4.w,a04);
            a10=fmaf(xv1.x,w0.x,a10); a10=fmaf(xv1.y,w0.y,a10); a10=fmaf(xv1.z,w0.z,a10); a10=fmaf(xv1.w,w0.w,a10);
            a11=fmaf(xv1.x,w1.x,a11); a11=fmaf(xv1.y,w1.y,a11); a11=fmaf(xv1.z,w1.z,a11); a11=fmaf(xv1.w,w1.w,a11);
            a12=fmaf(xv1.x,w2.x,a12); a12=fmaf(xv1.y,w2.y,a12); a12=fmaf(xv1.z,w2.z,a12); a12=fmaf(xv1.w,w2.w,a12);
            a13=fmaf(xv1.x,w3.x,a13); a13=fmaf(xv1.y,w3.y,a13); a13=fmaf(xv1.z,w3.z,a13); a13=fmaf(xv1.w,w3.w,a13);
            a14=fmaf(xv1.x,w4.x,a14); a14=fmaf(xv1.y,w4.y,a14); a14=fmaf(xv1.z,w4.z,a14); a14=fmaf(xv1.w,w4.w,a14);
        }
        const int r0 = 2*ty, r1 = 2*ty+1, cbase = 5*tx;
        p_s[buf][r0][cbase+0] = a00 + bias_s[cbase+0];
        p_s[buf][r0][cbase+1] = a01 + bias_s[cbase+1];
        p_s[buf][r0][cbase+2] = a02 + bias_s[cbase+2];
        p_s[buf][r0][cbase+3] = a03 + bias_s[cbase+3];
        p_s[buf][r0][cbase+4] = a04 + bias_s[cbase+4];
        p_s[buf][r1][cbase+0] = a10 + bias_s[cbase+0];
        p_s[buf][r1][cbase+1] = a11 + bias_s[cbase+1];
        p_s[buf][r1][cbase+2] = a12 + bias_s[cbase+2];
        p_s[buf][r1][cbase+3] = a13 + bias_s[cbase+3];
        p_s[buf][r1][cbase+4] = a14 + bias_s[cbase+4];
    };

    // ------------- recurrence registers (wave 0) -------------
    int bL = tid / NH; if (bL > 2) bL = 2;   // lanes 60..63 clamp (results discarded)
    const int j = tid % NH;
    const int base = bL * NH;
    float4 wi0, wi1, wi2, wi3, wi4;
    float4 wf0, wf1, wf2, wf3, wf4;
    float4 wg0, wg1, wg2, wg3, wg4;
    float4 wo0, wo1, wo2, wo3, wo4;
    float ht = 0.f, creg = 0.f, accum = 0.f;

    if (tid < 64) {
        const float* r0 = W_hh + (j)          * NH;
        const float* r1 = W_hh + (NH   + j)   * NH;
        const float* r2 = W_hh + (2*NH + j)   * NH;
        const float* r3 = W_hh + (3*NH + j)   * NH;
        wi0 = *(const float4*)(r0 + 0);  wi1 = *(const float4*)(r0 + 4);
        wi2 = *(const float4*)(r0 + 8);  wi3 = *(const float4*)(r0 + 12);
        wi4 = *(const float4*)(r0 + 16);
        wf0 = *(const float4*)(r1 + 0);  wf1 = *(const float4*)(r1 + 4);
        wf2 = *(const float4*)(r1 + 8);  wf3 = *(const float4*)(r1 + 12);
        wf4 = *(const float4*)(r1 + 16);
        wg0 = *(const float4*)(r2 + 0);  wg1 = *(const float4*)(r2 + 4);
        wg2 = *(const float4*)(r2 + 8);  wg3 = *(const float4*)(r2 + 12);
        wg4 = *(const float4*)(r2 + 16);
        wo0 = *(const float4*)(r3 + 0);  wo1 = *(const float4*)(r3 + 4);
        wo2 = *(const float4*)(r3 + 8);  wo3 = *(const float4*)(r3 + 12);
        wo4 = *(const float4*)(r3 + 16);
        OPAQ4(wi0); OPAQ4(wi1); OPAQ4(wi2); OPAQ4(wi3); OPAQ4(wi4);
        OPAQ4(wf0); OPAQ4(wf1); OPAQ4(wf2); OPAQ4(wf3); OPAQ4(wf4);
        OPAQ4(wg0); OPAQ4(wg1); OPAQ4(wg2); OPAQ4(wg3); OPAQ4(wg4);
        OPAQ4(wo0); OPAQ4(wo1); OPAQ4(wo2); OPAQ4(wo3); OPAQ4(wo4);
    } else {
        stage_x(0, 0);
    }
    __syncthreads();
    if (tid >= 64) {
        do_gemm(0);
        stage_x(1, 1);
    }
    __syncthreads();

    // 4 shuffles + 16 FMAs, split accumulators (a/b) to halve the dep chain
#define K4(VWI, VWF, VWG, VWO, KB)                                            \
    {                                                                         \
        float hk0 = __shfl(ht, base + (KB) + 0, 64);                          \
        float hk1 = __shfl(ht, base + (KB) + 1, 64);                          \
        float hk2 = __shfl(ht, base + (KB) + 2, 64);                          \
        float hk3 = __shfl(ht, base + (KB) + 3, 64);                          \
        s0a = fmaf(VWI.x, hk0, s0a); s0b = fmaf(VWI.y, hk1, s0b);             \
        s0a = fmaf(VWI.z, hk2, s0a); s0b = fmaf(VWI.w, hk3, s0b);             \
        s1a = fmaf(VWF.x, hk0, s1a); s1b = fmaf(VWF.y, hk1, s1b);             \
        s1a = fmaf(VWF.z, hk2, s1a); s1b = fmaf(VWF.w, hk3, s1b);             \
        s2a = fmaf(VWG.x, hk0, s2a); s2b = fmaf(VWG.y, hk1, s2b);             \
        s2a = fmaf(VWG.z, hk2, s2a); s2b = fmaf(VWG.w, hk3, s2b);             \
        s3a = fmaf(VWO.x, hk0, s3a); s3b = fmaf(VWO.y, hk1, s3b);             \
        s3a = fmaf(VWO.z, hk2, s3a); s3b = fmaf(VWO.w, hk3, s3b);             \
    }

#define TSTEP(TL, WL)                                                         \
    {                                                                         \
        const float* pr = pc + (TL) * PSTR;                                   \
        float s0a = pr[j],      s0b = 0.f;                                    \
        float s1a = pr[j + 20], s1b = 0.f;                                    \
        float s2a = pr[j + 40], s2b = 0.f;                                    \
        float s3a = pr[j + 60], s3b = 0.f;                                    \
        K4(wi0, wf0, wg0, wo0, 0)  K4(wi1, wf1, wg1, wo1, 4)                  \
        K4(wi2, wf2, wg2, wo2, 8)  K4(wi3, wf3, wg3, wo3, 12)                 \
        K4(wi4, wf4, wg4, wo4, 16)                                            \
        float gi = sigm(s0a + s0b);                                           \
        float gf = sigm(s1a + s1b);                                           \
        float gg = tanh_f(s2a + s2b);                                         \
        float go = sigm(s3a + s3b);                                           \
        creg = gf * creg + gi * gg;                                           \
        ht   = go * tanh_f(creg);                                             \
        accum = fmaf(ht, (WL), accum);                                        \
    }

    // ---------------- main pipeline ----------------
    for (int c = 0; c < NCHUNK; ++c) {
        if (tid < 64) {
            const int pb = c & 1;
            const float* wlp = W_lin + c * TC * NH + j;
            float wl0 = wlp[0 * NH], wl1 = wlp[1 * NH], wl2 = wlp[2 * NH], wl3 = wlp[3 * NH];
            float wl4 = wlp[4 * NH], wl5 = wlp[5 * NH], wl6 = wlp[6 * NH], wl7 = wlp[7 * NH];
            const float* pc = &p_s[pb][bL * TC][0];
            TSTEP(0, wl0) TSTEP(1, wl1) TSTEP(2, wl2) TSTEP(3, wl3)
            TSTEP(4, wl4) TSTEP(5, wl5) TSTEP(6, wl6) TSTEP(7, wl7)
        } else {
            float4 xr0, xr1;
            const bool doStage = (c + 2 < NCHUNK);
            if (doStage) {  // issue global loads for chunk c+2 early
                {
                    int r = wtid >> 4, k4 = wtid & 15;
                    int bb = b0 + (r >> 3);
                    int tt = (c + 2) * TC + (r & 7);
                    xr0 = make_float4(0.f, 0.f, 0.f, 0.f);
                    if (bb < NB) xr0 = *(const float4*)(x + ((size_t)bb * NT + tt) * NF + k4 * 4);
                }
                {
                    int id = wtid + 192;
                    int r = id >> 4, k4 = id & 15;
                    int bb = b0 + (r >> 3);
                    int tt = (c + 2) * TC + (r & 7);
                    xr1 = make_float4(0.f, 0.f, 0.f, 0.f);
                    if (bb < NB) xr1 = *(const float4*)(x + ((size_t)bb * NT + tt) * NF + k4 * 4);
                }
            }
            if (c + 1 < NCHUNK) do_gemm((c + 1) & 1);
            if (doStage) {
                {
                    int r = wtid >> 4, k4 = wtid & 15;
                    *(float4*)&x_s[c & 1][r][k4 * 4] = xr0;
                }
                {
                    int id = wtid + 192;
                    int r = id >> 4, k4 = id & 15;
                    *(float4*)&x_s[c & 1][r][k4 * 4] = xr1;
                }
            }
        }
        __syncthreads();
    }

    // ---------------- epilogue: out[b] = sum_j accum + b_lin ----------------
    if (tid < 64) {
        float tot = 0.f;
        #pragma unroll
        for (int k = 0; k < NH; ++k) tot += __shfl(accum, base + k, 64);
        if (j == 0 && tid < 60 && (b0 + bL) < NB) out[b0 + bL] = tot + b_lin[0];
    }
}

extern "C" void kernel_launch(void* const* d_in, const int* in_sizes, int n_in,
                              void* d_out, int out_size, void* d_ws, size_t ws_size,
                              hipStream_t stream) {
    const float* x     = (const float*)d_in[0];
    const float* W_ih  = (const float*)d_in[1];
    const float* W_hh  = (const float*)d_in[2];
    const float* b_ih  = (const float*)d_in[3];
    const float* b_hh  = (const float*)d_in[4];
    const float* W_lin = (const float*)d_in[5];
    const float* b_lin = (const float*)d_in[6];
    float* outp = (float*)d_out;
    mv_lstm_fused<<<NBLK, 256, 0, stream>>>(x, W_ih, W_hh, b_ih, b_hh, W_lin, b_lin, outp);
}